// Round 2
// baseline (165.471 us; speedup 1.0000x reference)
//
#include <hip/hip_runtime.h>
#include <hip/hip_bf16.h>

#define TOKENS 64
#define IN_F 8192
#define OUT_F 8192
#define CB 256

typedef _Float16 half8 __attribute__((ext_vector_type(8)));
typedef float f32x4 __attribute__((ext_vector_type(4)));

// ---------------------------------------------------------------------------
// Kernel 1: xh = FWHT(x * SU) * (1/sqrt(IN_F) * Wscale[0])  -> fp16
// One block per token row. 256 threads; each thread holds 32 elements:
//   e = r*256 + t   (r = e[8:13] register bits, t[0:6]=lane, t[6:8]=wave)
// FWHT stages commute (independent tensor factors), so order: register bits
// 8..12, lane bits 0..5 via shfl_xor, wave bits 6..7 via one LDS H4 pass.
// ---------------------------------------------------------------------------
__global__ __launch_bounds__(256) void k_fwht_in(const float* __restrict__ x,
                                                 const float* __restrict__ SU,
                                                 const float* __restrict__ Wscale,
                                                 _Float16* __restrict__ xh)
{
    __shared__ float buf[256 * 33];
    const int t    = threadIdx.x;
    const int lane = t & 63;
    const int w    = t >> 6;
    const int row  = blockIdx.x;

    float v[32];
    const float* xr = x + row * IN_F;
#pragma unroll
    for (int r = 0; r < 32; ++r) {
        int e = r * 256 + t;
        v[r] = xr[e] * SU[e];
    }
    // group A: bits 8..12 (register index)
#pragma unroll
    for (int h = 1; h < 32; h <<= 1) {
#pragma unroll
        for (int r = 0; r < 32; ++r) {
            if ((r & h) == 0) {
                float a = v[r], b = v[r + h];
                v[r] = a + b;
                v[r + h] = a - b;
            }
        }
    }
    // group B: bits 0..5 (lane bits) via shfl_xor
#pragma unroll
    for (int m = 1; m < 64; m <<= 1) {
        bool upper = (lane & m) != 0;
#pragma unroll
        for (int r = 0; r < 32; ++r) {
            float p = __shfl_xor(v[r], m, 64);
            v[r] = upper ? (p - v[r]) : (v[r] + p);
        }
    }
    // group C: bits 6..7 (wave bits) via LDS, combined H4
#pragma unroll
    for (int r = 0; r < 32; ++r) buf[t * 33 + r] = v[r];
    __syncthreads();
    {
        float s1 = (w & 1) ? -1.f : 1.f;
        float s2 = (w & 2) ? -1.f : 1.f;
        float s3 = s1 * s2;
#pragma unroll
        for (int r = 0; r < 32; ++r) {
            float a0 = buf[(0 * 64 + lane) * 33 + r];
            float a1 = buf[(1 * 64 + lane) * 33 + r];
            float a2 = buf[(2 * 64 + lane) * 33 + r];
            float a3 = buf[(3 * 64 + lane) * 33 + r];
            v[r] = a0 + s1 * a1 + s2 * a2 + s3 * a3;
        }
    }
    const float scale = 0.011048543456039806f * Wscale[0];  // 1/sqrt(8192) * Wscale
    _Float16* xo = xh + row * IN_F;
#pragma unroll
    for (int r = 0; r < 32; ++r) {
        xo[r * 256 + t] = (_Float16)(v[r] * scale);
    }
}

// ---------------------------------------------------------------------------
// Kernel 2: fused dequant GEMM  y[t, o] = sum_k xh[t,k] * grid[Qidxs[o,k/8]][k%8]
// grid: 512 blocks x 256 threads. Block covers N_block=16 output features,
// all 64 tokens. 4 waves split K 4-ways (2048 each); LDS reduce at the end.
// Wave tile: M=64 (4 m-tiles) x N=16 (1 n-tile), 16x16x32 f16 MFMA.
// B-fragment = one codebook entry per lane (CODESZ==8 == frag k-slice of 8).
// Pipeline invariant (FIXED from R0): at step s, MFMA consumes b_c == b(s);
// the LDS gather in step s produces b(s+1) from qA == q(s+1); rotation AFTER
// the MFMA. R0 consumed b_n (= b(s+1)) -> one-step-shifted B-stream, absmax 596.
// ---------------------------------------------------------------------------
__global__ __launch_bounds__(256) void k_qgemm(const _Float16* __restrict__ xh,
                                               const int* __restrict__ Qidxs,
                                               const float* __restrict__ grid,
                                               float* __restrict__ y)
{
    __shared__ __align__(16) _Float16 glds[CB * 8];   // 4 KB fp16 codebook
    __shared__ float red[4 * 64 * 18];                // 18 KB reduce buffer

    const int tid = threadIdx.x;

    // stage codebook -> LDS as fp16 (256 threads, one entry each)
    {
        const float4* gp = (const float4*)grid + tid * 2;
        float4 g0 = gp[0];
        float4 g1 = gp[1];
        _Float16* gl = &glds[tid * 8];
        gl[0] = (_Float16)g0.x; gl[1] = (_Float16)g0.y;
        gl[2] = (_Float16)g0.z; gl[3] = (_Float16)g0.w;
        gl[4] = (_Float16)g1.x; gl[5] = (_Float16)g1.y;
        gl[6] = (_Float16)g1.z; gl[7] = (_Float16)g1.w;
    }
    __syncthreads();

    const int lane = tid & 63;
    const int w    = tid >> 6;       // wave id -> K chunk
    const int col  = lane & 15;      // n within tile / m within A frag
    const int quad = lane >> 4;      // k-slice selector
    const int n0   = blockIdx.x * 16;
    const int n    = n0 + col;

    const int kbase = w * 2048;                 // wave's K range
    const int jbase = (kbase >> 3) + quad;      // Qidxs column index
    const int* qrow = Qidxs + n * 1024;
    const _Float16* xa = xh + col * IN_F + kbase + quad * 8;

    f32x4 acc[4] = {};

    // pipeline state: b_c = b(s), qA = q(s+1), qB = q(s+2)
    int qA = qrow[jbase + 4];   // q(1)
    int qB = qrow[jbase + 8];   // q(2)
    half8 b_c = *(const half8*)&glds[qrow[jbase] * 8];   // b(0)
    half8 a_c[4];
#pragma unroll
    for (int m = 0; m < 4; ++m)
        a_c[m] = *(const half8*)(xa + m * 16 * IN_F);    // a(0)

#pragma unroll 4
    for (int s = 0; s < 64; ++s) {
        int sq = (s + 3 < 64) ? s + 3 : 63;
        int qn = qrow[jbase + sq * 4];                 // q(s+3), global load
        half8 b_n = *(const half8*)&glds[qA * 8];      // b(s+1), LDS gather
        int sa = (s + 1 < 64) ? s + 1 : 63;
        half8 a_n[4];
#pragma unroll
        for (int m = 0; m < 4; ++m)
            a_n[m] = *(const half8*)(xa + m * 16 * IN_F + sa * 32);  // a(s+1)
#pragma unroll
        for (int m = 0; m < 4; ++m)
            acc[m] = __builtin_amdgcn_mfma_f32_16x16x32_f16(a_c[m], b_c, acc[m], 0, 0, 0);
        b_c = b_n;              // rotate AFTER consumption
        qA = qB; qB = qn;
#pragma unroll
        for (int m = 0; m < 4; ++m) a_c[m] = a_n[m];
    }

    __syncthreads();
    // C/D layout: col=lane&15 (=n), row=quad*4+i (=m within 16) [m89-verified]
#pragma unroll
    for (int m = 0; m < 4; ++m) {
#pragma unroll
        for (int i = 0; i < 4; ++i) {
            int r = m * 16 + quad * 4 + i;             // token index
            red[(w * 64 + r) * 18 + col] = acc[m][i];
        }
    }
    __syncthreads();
#pragma unroll
    for (int jj = 0; jj < 4; ++jj) {
        int idx = tid + jj * 256;
        int rr = idx >> 4, cc = idx & 15;
        float s = red[(0 * 64 + rr) * 18 + cc] + red[(1 * 64 + rr) * 18 + cc]
                + red[(2 * 64 + rr) * 18 + cc] + red[(3 * 64 + rr) * 18 + cc];
        y[rr * OUT_F + n0 + cc] = s;
    }
}

// ---------------------------------------------------------------------------
// Kernel 3: out = FWHT(y) * (1/sqrt(OUT_F)) * SV + bias   (same FWHT hybrid)
// ---------------------------------------------------------------------------
__global__ __launch_bounds__(256) void k_fwht_out(const float* __restrict__ y,
                                                  const float* __restrict__ SV,
                                                  const float* __restrict__ bias,
                                                  float* __restrict__ out)
{
    __shared__ float buf[256 * 33];
    const int t    = threadIdx.x;
    const int lane = t & 63;
    const int w    = t >> 6;
    const int row  = blockIdx.x;

    float v[32];
    const float* yr = y + row * OUT_F;
#pragma unroll
    for (int r = 0; r < 32; ++r) v[r] = yr[r * 256 + t];
#pragma unroll
    for (int h = 1; h < 32; h <<= 1) {
#pragma unroll
        for (int r = 0; r < 32; ++r) {
            if ((r & h) == 0) {
                float a = v[r], b = v[r + h];
                v[r] = a + b;
                v[r + h] = a - b;
            }
        }
    }
#pragma unroll
    for (int m = 1; m < 64; m <<= 1) {
        bool upper = (lane & m) != 0;
#pragma unroll
        for (int r = 0; r < 32; ++r) {
            float p = __shfl_xor(v[r], m, 64);
            v[r] = upper ? (p - v[r]) : (v[r] + p);
        }
    }
#pragma unroll
    for (int r = 0; r < 32; ++r) buf[t * 33 + r] = v[r];
    __syncthreads();
    {
        float s1 = (w & 1) ? -1.f : 1.f;
        float s2 = (w & 2) ? -1.f : 1.f;
        float s3 = s1 * s2;
#pragma unroll
        for (int r = 0; r < 32; ++r) {
            float a0 = buf[(0 * 64 + lane) * 33 + r];
            float a1 = buf[(1 * 64 + lane) * 33 + r];
            float a2 = buf[(2 * 64 + lane) * 33 + r];
            float a3 = buf[(3 * 64 + lane) * 33 + r];
            v[r] = a0 + s1 * a1 + s2 * a2 + s3 * a3;
        }
    }
    const float scale = 0.011048543456039806f;  // 1/sqrt(8192)
    float* oo = out + row * OUT_F;
#pragma unroll
    for (int r = 0; r < 32; ++r) {
        int e = r * 256 + t;
        oo[e] = v[r] * scale * SV[e] + bias[e];
    }
}

extern "C" void kernel_launch(void* const* d_in, const int* in_sizes, int n_in,
                              void* d_out, int out_size, void* d_ws, size_t ws_size,
                              hipStream_t stream) {
    const float* x      = (const float*)d_in[0];
    const float* SU     = (const float*)d_in[1];
    const float* SV     = (const float*)d_in[2];
    const float* grid   = (const float*)d_in[3];
    const float* Wscale = (const float*)d_in[4];
    const float* bias   = (const float*)d_in[5];
    const int*   Qidxs  = (const int*)d_in[6];
    float* out = (float*)d_out;

    _Float16* xh = (_Float16*)d_ws;                                    // 1 MB
    float*    y  = (float*)((char*)d_ws + (size_t)TOKENS * IN_F * 2);  // 2 MB

    k_fwht_in<<<TOKENS, 256, 0, stream>>>(x, SU, Wscale, xh);
    k_qgemm<<<OUT_F / 16, 256, 0, stream>>>(xh, Qidxs, grid, y);
    k_fwht_out<<<TOKENS, 256, 0, stream>>>(y, SV, bias, out);
}

// Round 4
// 147.573 us; speedup vs baseline: 1.1213x; 1.1213x over previous
//
#include <hip/hip_runtime.h>
#include <hip/hip_bf16.h>

#define TOKENS 64
#define IN_F 8192
#define OUT_F 8192
#define CB 256

typedef _Float16 half8 __attribute__((ext_vector_type(8)));
typedef float f32x4 __attribute__((ext_vector_type(4)));

// ---------------------------------------------------------------------------
// Kernel 1: xh = FWHT(x * SU) * (1/sqrt(IN_F) * Wscale[0])  -> fp16, stored in
// MFMA-A-FRAGMENT ORDER:
//   xh_frag[((ks*4 + mt)*64 + quad*16 + l15)*8 + j]
//     = xh_row[mt*16 + l15][ks*32 + quad*8 + j]
// so k2's A-fragment load is 64 lanes x 16B CONTIGUOUS (1KB burst).
// One block per token row; FWHT as in R1 (verified); then an LDS round-trip
// (bank-even padded layout) to form half8 chunks, then scattered 16B stores.
// ---------------------------------------------------------------------------
__global__ __launch_bounds__(256) void k_fwht_in(const float* __restrict__ x,
                                                 const float* __restrict__ SU,
                                                 const float* __restrict__ Wscale,
                                                 _Float16* __restrict__ xh_frag)
{
    __shared__ float buf[256 * 33];
    // padded fp16 row buffer: idx(c) = (c&31) + (c>>5)*40  (max 10232 halves)
    __shared__ _Float16 xrowP[256 * 40];
    const int t    = threadIdx.x;
    const int lane = t & 63;
    const int w    = t >> 6;
    const int row  = blockIdx.x;

    float v[32];
    const float* xr = x + row * IN_F;
#pragma unroll
    for (int r = 0; r < 32; ++r) {
        int e = r * 256 + t;
        v[r] = xr[e] * SU[e];
    }
    // FWHT group A: bits 8..12 (register index)
#pragma unroll
    for (int h = 1; h < 32; h <<= 1) {
#pragma unroll
        for (int r = 0; r < 32; ++r) {
            if ((r & h) == 0) {
                float a = v[r], b = v[r + h];
                v[r] = a + b;
                v[r + h] = a - b;
            }
        }
    }
    // FWHT group B: bits 0..5 (lane bits) via shfl_xor
#pragma unroll
    for (int m = 1; m < 64; m <<= 1) {
        bool upper = (lane & m) != 0;
#pragma unroll
        for (int r = 0; r < 32; ++r) {
            float p = __shfl_xor(v[r], m, 64);
            v[r] = upper ? (p - v[r]) : (v[r] + p);
        }
    }
    // FWHT group C: bits 6..7 (wave bits) via LDS H4
#pragma unroll
    for (int r = 0; r < 32; ++r) buf[t * 33 + r] = v[r];
    __syncthreads();
    {
        float s1 = (w & 1) ? -1.f : 1.f;
        float s2 = (w & 2) ? -1.f : 1.f;
        float s3 = s1 * s2;
#pragma unroll
        for (int r = 0; r < 32; ++r) {
            float a0 = buf[(0 * 64 + lane) * 33 + r];
            float a1 = buf[(1 * 64 + lane) * 33 + r];
            float a2 = buf[(2 * 64 + lane) * 33 + r];
            float a3 = buf[(3 * 64 + lane) * 33 + r];
            v[r] = a0 + s1 * a1 + s2 * a2 + s3 * a3;
        }
    }
    const float scale = 0.011048543456039806f * Wscale[0];  // 1/sqrt(8192)*Wscale
    // scatter into padded LDS as fp16: col c = r*256 + t
#pragma unroll
    for (int r = 0; r < 32; ++r) {
        int idx = (t & 31) + (r * 8 + (t >> 5)) * 40;   // (c&31) + (c>>5)*40
        xrowP[idx] = (_Float16)(v[r] * scale);
    }
    __syncthreads();
    // each thread t owns kstep ks = t (32 cols), emits 4 x half8 fragment slices
    {
        const int mt  = row >> 4;
        const int l15 = row & 15;
        _Float16* base = xh_frag + ((size_t)(t * 4 + mt) * 64 + l15) * 8;
#pragma unroll
        for (int g = 0; g < 4; ++g) {                    // g = quad = (c>>3)&3
            half8 val = *(const half8*)&xrowP[t * 40 + g * 8];
            *(half8*)(base + g * 16 * 8) = val;
        }
    }
}

// ---------------------------------------------------------------------------
// Kernel 2: fused dequant GEMM, y_part[p] += xh * W_hat^T over K-part p.
// Grid: 512 blocks = 128 n-groups x 4 K-parts. Block: 4 waves; waves split the
// K-part 4 ways (512 k each = 16 k-steps). Wave tile: M=64 (4 m-frags) x N=64
// (4 n-tiles) -> 16 MFMAs / k-step, acc 64 VGPR.
// A: contiguous 1KB fragment loads from xh_frag (global, L2-resident), 2-deep
//    prefetch. B: per-lane Qidxs dword (2-iter distance) -> LDS codebook
//    16B gather (1-iter distance). No barriers in the K-loop.
// Epilogue: 4-wave LDS tree-reduce -> y_part[p] (64x8192 f32 per part).
// ---------------------------------------------------------------------------
__global__ __launch_bounds__(256, 2) void k_qgemm(const _Float16* __restrict__ xh_frag,
                                                  const int* __restrict__ Qidxs,
                                                  const float* __restrict__ grid,
                                                  float* __restrict__ y_part)
{
    __shared__ __align__(16) _Float16 glds[CB * 8];   // 4 KB fp16 codebook
    __shared__ float red[4 * 64 * 68];                // 68-stride: bank-even

    const int tid = threadIdx.x;

    // stage codebook -> LDS fp16
    {
        const float4* gp = (const float4*)grid + tid * 2;
        float4 g0 = gp[0];
        float4 g1 = gp[1];
        _Float16* gl = &glds[tid * 8];
        gl[0] = (_Float16)g0.x; gl[1] = (_Float16)g0.y;
        gl[2] = (_Float16)g0.z; gl[3] = (_Float16)g0.w;
        gl[4] = (_Float16)g1.x; gl[5] = (_Float16)g1.y;
        gl[6] = (_Float16)g1.z; gl[7] = (_Float16)g1.w;
    }
    __syncthreads();

    const int lane = tid & 63;
    const int w    = tid >> 6;        // wave id -> K sub-chunk
    const int col  = lane & 15;
    const int quad = lane >> 4;
    const int g    = blockIdx.x >> 2; // n-group (128)
    const int p    = blockIdx.x & 3;  // K-part (4)
    const int n0   = g * 64;

    // Qidxs pointers: per n-tile, this lane reads row n0+nt*16+col,
    // int column jb + s*4,  jb = p*256 + w*64 + quad
    const int jb = p * 256 + w * 64 + quad;
    const int* qp[4];
#pragma unroll
    for (int nt = 0; nt < 4; ++nt)
        qp[nt] = Qidxs + (size_t)(n0 + nt * 16 + col) * 1024 + jb;

    // A fragment base: global kstep Ks = p*64 + w*16 + s
    const _Float16* abase = xh_frag + ((size_t)(p * 64 + w * 16) * 4 * 64 + lane) * 8;
    // fragment (s, mt) at abase + (s*4 + mt)*64*8 halves

    f32x4 acc[4][4] = {};   // [nt][mt]

    // ---- pipeline prologue ----
    int q1[4], q2[4];
    half8 b_c[4];
#pragma unroll
    for (int nt = 0; nt < 4; ++nt) {
        int q0 = qp[nt][0];
        q1[nt] = qp[nt][4];
        q2[nt] = qp[nt][8];
        b_c[nt] = *(const half8*)&glds[q0 * 8];
    }
    half8 a_c[4], a_n[4];
#pragma unroll
    for (int mt = 0; mt < 4; ++mt) {
        a_c[mt] = *(const half8*)(abase + (size_t)(0 * 4 + mt) * 512);
        a_n[mt] = *(const half8*)(abase + (size_t)(1 * 4 + mt) * 512);
    }

#pragma unroll 4
    for (int s = 0; s < 16; ++s) {
        const int s3 = (s + 3 < 16 ? s + 3 : 15) * 4;
        const int s2 = (s + 2 < 16 ? s + 2 : 15);
        int qn[4];
        half8 b_n[4], a_nn[4];
#pragma unroll
        for (int nt = 0; nt < 4; ++nt) qn[nt] = qp[nt][s3];          // q(s+3)
#pragma unroll
        for (int nt = 0; nt < 4; ++nt)
            b_n[nt] = *(const half8*)&glds[q1[nt] * 8];              // b(s+1)
#pragma unroll
        for (int mt = 0; mt < 4; ++mt)
            a_nn[mt] = *(const half8*)(abase + (size_t)(s2 * 4 + mt) * 512); // a(s+2)
#pragma unroll
        for (int nt = 0; nt < 4; ++nt)
#pragma unroll
            for (int mt = 0; mt < 4; ++mt)
                acc[nt][mt] = __builtin_amdgcn_mfma_f32_16x16x32_f16(
                    a_c[mt], b_c[nt], acc[nt][mt], 0, 0, 0);
#pragma unroll
        for (int nt = 0; nt < 4; ++nt) { b_c[nt] = b_n[nt]; q1[nt] = q2[nt]; q2[nt] = qn[nt]; }
#pragma unroll
        for (int mt = 0; mt < 4; ++mt) { a_c[mt] = a_n[mt]; a_n[mt] = a_nn[mt]; }
    }

    // ---- epilogue: 4-wave reduce over K sub-chunks ----
    // C/D layout: token r = mt*16 + quad*4 + i, feature c = nt*16 + col
#pragma unroll
    for (int nt = 0; nt < 4; ++nt)
#pragma unroll
        for (int mt = 0; mt < 4; ++mt)
#pragma unroll
            for (int i = 0; i < 4; ++i) {
                int r = mt * 16 + quad * 4 + i;
                int c = nt * 16 + col;
                red[(w * 64 + r) * 68 + c] = acc[nt][mt][i];
            }
    __syncthreads();
    float* yp = y_part + (size_t)p * TOKENS * OUT_F;
#pragma unroll
    for (int j = 0; j < 16; ++j) {
        int idx = j * 256 + tid;
        int rr = idx >> 6, cc = idx & 63;
        float s = (red[(0 * 64 + rr) * 68 + cc] + red[(1 * 64 + rr) * 68 + cc])
                + (red[(2 * 64 + rr) * 68 + cc] + red[(3 * 64 + rr) * 68 + cc]);
        yp[(size_t)rr * OUT_F + n0 + cc] = s;
    }
}

// ---------------------------------------------------------------------------
// Kernel 3: fold 4 K-part partials, FWHT, * 1/sqrt(OUT_F) * SV + bias
// ---------------------------------------------------------------------------
__global__ __launch_bounds__(256) void k_fwht_out(const float* __restrict__ y_part,
                                                  const float* __restrict__ SV,
                                                  const float* __restrict__ bias,
                                                  float* __restrict__ out)
{
    __shared__ float buf[256 * 33];
    const int t    = threadIdx.x;
    const int lane = t & 63;
    const int w    = t >> 6;
    const int row  = blockIdx.x;

    const float* y0 = y_part + (size_t)row * OUT_F;
    const size_t ps = (size_t)TOKENS * OUT_F;

    float v[32];
#pragma unroll
    for (int r = 0; r < 32; ++r) {
        int e = r * 256 + t;
        v[r] = (y0[e] + y0[e + ps]) + (y0[e + 2 * ps] + y0[e + 3 * ps]);
    }
#pragma unroll
    for (int h = 1; h < 32; h <<= 1) {
#pragma unroll
        for (int r = 0; r < 32; ++r) {
            if ((r & h) == 0) {
                float a = v[r], b = v[r + h];
                v[r] = a + b;
                v[r + h] = a - b;
            }
        }
    }
#pragma unroll
    for (int m = 1; m < 64; m <<= 1) {
        bool upper = (lane & m) != 0;
#pragma unroll
        for (int r = 0; r < 32; ++r) {
            float p = __shfl_xor(v[r], m, 64);
            v[r] = upper ? (p - v[r]) : (v[r] + p);
        }
    }
#pragma unroll
    for (int r = 0; r < 32; ++r) buf[t * 33 + r] = v[r];
    __syncthreads();
    {
        float s1 = (w & 1) ? -1.f : 1.f;
        float s2 = (w & 2) ? -1.f : 1.f;
        float s3 = s1 * s2;
#pragma unroll
        for (int r = 0; r < 32; ++r) {
            float a0 = buf[(0 * 64 + lane) * 33 + r];
            float a1 = buf[(1 * 64 + lane) * 33 + r];
            float a2 = buf[(2 * 64 + lane) * 33 + r];
            float a3 = buf[(3 * 64 + lane) * 33 + r];
            v[r] = a0 + s1 * a1 + s2 * a2 + s3 * a3;
        }
    }
    const float scale = 0.011048543456039806f;  // 1/sqrt(8192)
    float* oo = out + (size_t)row * OUT_F;
#pragma unroll
    for (int r = 0; r < 32; ++r) {
        int e = r * 256 + t;
        oo[e] = v[r] * scale * SV[e] + bias[e];
    }
}

extern "C" void kernel_launch(void* const* d_in, const int* in_sizes, int n_in,
                              void* d_out, int out_size, void* d_ws, size_t ws_size,
                              hipStream_t stream) {
    const float* x      = (const float*)d_in[0];
    const float* SU     = (const float*)d_in[1];
    const float* SV     = (const float*)d_in[2];
    const float* grid   = (const float*)d_in[3];
    const float* Wscale = (const float*)d_in[4];
    const float* bias   = (const float*)d_in[5];
    const int*   Qidxs  = (const int*)d_in[6];
    float* out = (float*)d_out;

    _Float16* xh_frag = (_Float16*)d_ws;                                 // 1 MB
    float*    y_part  = (float*)((char*)d_ws + ((size_t)1 << 20));       // 4 x 2 MB

    k_fwht_in<<<TOKENS, 256, 0, stream>>>(x, SU, Wscale, xh_frag);
    k_qgemm<<<512, 256, 0, stream>>>(xh_frag, Qidxs, grid, y_part);
    k_fwht_out<<<TOKENS, 256, 0, stream>>>(y_part, SV, bias, out);
}

// Round 6
// 121.452 us; speedup vs baseline: 1.3624x; 1.2151x over previous
//
#include <hip/hip_runtime.h>
#include <hip/hip_bf16.h>

#define TOKENS 64
#define IN_F 8192
#define OUT_F 8192
#define CB 256

typedef _Float16 half8 __attribute__((ext_vector_type(8)));
typedef float f32x4 __attribute__((ext_vector_type(4)));

// ---------------------------------------------------------------------------
// Kernel 0: repack Qidxs (OUT_F x 1024 int, row-major) into "GEMM order" so
// k2's index loads are perfectly coalesced:
//   Qpack[int4 idx ((bid*4 + w)*16 + s)*64 + lane] =
//     { Qidxs[n0+nt*16+col][p*256 + w*64 + s*4 + quad] : nt=0..3 }
//   with bid = g*4+p, n0 = g*64, col = lane&15, quad = lane>>4.
// R4 evidence: k2 FETCH=123MB = ~4x Qidxs (64-row x 4KB-stride scatter
// conflict-misses L2; A-stream flushes L1 between the 4 uses of each line).
// R5 BUG (absmax 1033): phase 1 loaded only 16 of each 64-int chunk
// (4 x int4 at stride 16) leaving 3/4 of sq uninitialized. Fixed: 16
// consecutive int4 loads per thread.
// ---------------------------------------------------------------------------
#define QP_STRIDE 261   // phase-2 bank = (16nt+5col+quad+c)%32, ~2-way max
__global__ __launch_bounds__(256, 2) void k_qpack(const int* __restrict__ Qidxs,
                                                  int* __restrict__ Qpack)
{
    __shared__ int sq[64 * QP_STRIDE];   // 65.25 KB -> 2 blocks/CU
    const int tid = threadIdx.x;
    const int bid = blockIdx.x;
    const int g = bid >> 2, p = bid & 3;
    const int n0 = g * 64;

    // phase 1: stage slice rows n0..n0+63, int cols p*256..p*256+255 (64 KB)
    // thread t: row r = t>>2, 64-int chunk at (t&3)*64 = 16 consecutive int4.
    {
        const int r  = tid >> 2;
        const int c0 = (tid & 3) * 64;
        const int4* src4 = (const int4*)(Qidxs + (size_t)(n0 + r) * 1024 + p * 256 + c0);
        int* dst = &sq[r * QP_STRIDE + c0];
#pragma unroll
        for (int i = 0; i < 16; ++i) {
            int4 vv = src4[i];
            dst[i * 4 + 0] = vv.x; dst[i * 4 + 1] = vv.y;
            dst[i * 4 + 2] = vv.z; dst[i * 4 + 3] = vv.w;
        }
    }
    __syncthreads();
    // phase 2: 4096 int4 outputs; o = j*256+tid -> lane=o&63, s=(o>>6)&15, w=o>>10
    int4* qout = (int4*)Qpack + (size_t)bid * 4096;
#pragma unroll
    for (int j = 0; j < 16; ++j) {
        int o = j * 256 + tid;
        int lane = o & 63, s = (o >> 6) & 15, w = o >> 10;
        int col = lane & 15, quad = lane >> 4;
        int c = w * 64 + s * 4 + quad;
        int4 vv;
        vv.x = sq[(0 * 16 + col) * QP_STRIDE + c];
        vv.y = sq[(1 * 16 + col) * QP_STRIDE + c];
        vv.z = sq[(2 * 16 + col) * QP_STRIDE + c];
        vv.w = sq[(3 * 16 + col) * QP_STRIDE + c];
        qout[(w * 16 + s) * 64 + lane] = vv;   // 64 lanes x 16B contiguous
    }
}

// ---------------------------------------------------------------------------
// Kernel 1: xh = FWHT(x * SU) * (1/sqrt(IN_F) * Wscale[0])  -> fp16, stored in
// MFMA-A-FRAGMENT ORDER (k2 A-load = 64 lanes x 16B contiguous):
//   xh_frag[((ks*4 + mt)*64 + quad*16 + l15)*8 + j]
//     = xh_row[mt*16 + l15][ks*32 + quad*8 + j]
// ---------------------------------------------------------------------------
__global__ __launch_bounds__(256) void k_fwht_in(const float* __restrict__ x,
                                                 const float* __restrict__ SU,
                                                 const float* __restrict__ Wscale,
                                                 _Float16* __restrict__ xh_frag)
{
    __shared__ float buf[256 * 33];
    __shared__ _Float16 xrowP[256 * 40];
    const int t    = threadIdx.x;
    const int lane = t & 63;
    const int w    = t >> 6;
    const int row  = blockIdx.x;

    float v[32];
    const float* xr = x + row * IN_F;
#pragma unroll
    for (int r = 0; r < 32; ++r) {
        int e = r * 256 + t;
        v[r] = xr[e] * SU[e];
    }
    // FWHT group A: bits 8..12 (register index)
#pragma unroll
    for (int h = 1; h < 32; h <<= 1) {
#pragma unroll
        for (int r = 0; r < 32; ++r) {
            if ((r & h) == 0) {
                float a = v[r], b = v[r + h];
                v[r] = a + b;
                v[r + h] = a - b;
            }
        }
    }
    // FWHT group B: bits 0..5 (lane bits) via shfl_xor
#pragma unroll
    for (int m = 1; m < 64; m <<= 1) {
        bool upper = (lane & m) != 0;
#pragma unroll
        for (int r = 0; r < 32; ++r) {
            float p = __shfl_xor(v[r], m, 64);
            v[r] = upper ? (p - v[r]) : (v[r] + p);
        }
    }
    // FWHT group C: bits 6..7 (wave bits) via LDS H4
#pragma unroll
    for (int r = 0; r < 32; ++r) buf[t * 33 + r] = v[r];
    __syncthreads();
    {
        float s1 = (w & 1) ? -1.f : 1.f;
        float s2 = (w & 2) ? -1.f : 1.f;
        float s3 = s1 * s2;
#pragma unroll
        for (int r = 0; r < 32; ++r) {
            float a0 = buf[(0 * 64 + lane) * 33 + r];
            float a1 = buf[(1 * 64 + lane) * 33 + r];
            float a2 = buf[(2 * 64 + lane) * 33 + r];
            float a3 = buf[(3 * 64 + lane) * 33 + r];
            v[r] = a0 + s1 * a1 + s2 * a2 + s3 * a3;
        }
    }
    const float scale = 0.011048543456039806f * Wscale[0];  // 1/sqrt(8192)*Wscale
#pragma unroll
    for (int r = 0; r < 32; ++r) {
        int idx = (t & 31) + (r * 8 + (t >> 5)) * 40;   // (c&31) + (c>>5)*40
        xrowP[idx] = (_Float16)(v[r] * scale);
    }
    __syncthreads();
    {
        const int mt  = row >> 4;
        const int l15 = row & 15;
        _Float16* base = xh_frag + ((size_t)(t * 4 + mt) * 64 + l15) * 8;
#pragma unroll
        for (int g = 0; g < 4; ++g) {
            half8 val = *(const half8*)&xrowP[t * 40 + g * 8];
            *(half8*)(base + g * 16 * 8) = val;
        }
    }
}

// ---------------------------------------------------------------------------
// Kernel 2: fused dequant GEMM, y_part[p] = xh * W_hat^T over K-part p.
// Grid: 512 blocks = 128 n-groups x 4 K-parts; 4 waves split the K-part.
// Wave tile M=64 x N=64, 16x16x32 f16 MFMA, acc 64 VGPR.
// Index stream: ONE coalesced int4/lane/k-step from Qpack (R4: was 4 scattered
// dwords -> 4x HBM refetch). B: LDS codebook 16B gather. A: contiguous 1KB
// fragment loads. No barriers in the K-loop.
// ---------------------------------------------------------------------------
__global__ __launch_bounds__(256, 2) void k_qgemm(const _Float16* __restrict__ xh_frag,
                                                  const int* __restrict__ Qpack,
                                                  const float* __restrict__ grid,
                                                  float* __restrict__ y_part)
{
    __shared__ __align__(16) _Float16 glds[CB * 8];   // 4 KB fp16 codebook
    __shared__ float red[4 * 64 * 68];                // 68-stride: bank-even

    const int tid = threadIdx.x;

    // stage codebook -> LDS fp16
    {
        const float4* gp = (const float4*)grid + tid * 2;
        float4 g0 = gp[0];
        float4 g1 = gp[1];
        _Float16* gl = &glds[tid * 8];
        gl[0] = (_Float16)g0.x; gl[1] = (_Float16)g0.y;
        gl[2] = (_Float16)g0.z; gl[3] = (_Float16)g0.w;
        gl[4] = (_Float16)g1.x; gl[5] = (_Float16)g1.y;
        gl[6] = (_Float16)g1.z; gl[7] = (_Float16)g1.w;
    }
    __syncthreads();

    const int lane = tid & 63;
    const int w    = tid >> 6;        // wave id -> K sub-chunk
    const int col  = lane & 15;
    const int quad = lane >> 4;
    const int g    = blockIdx.x >> 2; // n-group (128)
    const int p    = blockIdx.x & 3;  // K-part (4)
    const int n0   = g * 64;

    // packed index stream: q(s) at qbase[s*64]
    const int4* qbase = (const int4*)Qpack + (size_t)blockIdx.x * 4096 + w * 1024 + lane;

    // A fragment base: global kstep Ks = p*64 + w*16 + s; frag (s,mt) at +(s*4+mt)*512
    const _Float16* abase = xh_frag + ((size_t)(p * 64 + w * 16) * 4 * 64 + lane) * 8;

    f32x4 acc[4][4] = {};   // [nt][mt]

    // ---- pipeline prologue: b_c = b(0), qv1 = q(1), qv2 = q(2) ----
    int4 qv1, qv2;
    half8 b_c[4];
    {
        int4 qv0 = qbase[0];
        qv1 = qbase[64];
        qv2 = qbase[128];
        b_c[0] = *(const half8*)&glds[qv0.x * 8];
        b_c[1] = *(const half8*)&glds[qv0.y * 8];
        b_c[2] = *(const half8*)&glds[qv0.z * 8];
        b_c[3] = *(const half8*)&glds[qv0.w * 8];
    }
    half8 a_c[4], a_n[4];
#pragma unroll
    for (int mt = 0; mt < 4; ++mt) {
        a_c[mt] = *(const half8*)(abase + (size_t)(0 * 4 + mt) * 512);
        a_n[mt] = *(const half8*)(abase + (size_t)(1 * 4 + mt) * 512);
    }

#pragma unroll 4
    for (int s = 0; s < 16; ++s) {
        const int s3 = (s + 3 < 16 ? s + 3 : 15);
        const int s2 = (s + 2 < 16 ? s + 2 : 15);
        int4 qn = qbase[s3 * 64];                        // q(s+3), coalesced int4
        half8 b_n[4], a_nn[4];
        b_n[0] = *(const half8*)&glds[qv1.x * 8];        // b(s+1)
        b_n[1] = *(const half8*)&glds[qv1.y * 8];
        b_n[2] = *(const half8*)&glds[qv1.z * 8];
        b_n[3] = *(const half8*)&glds[qv1.w * 8];
#pragma unroll
        for (int mt = 0; mt < 4; ++mt)
            a_nn[mt] = *(const half8*)(abase + (size_t)(s2 * 4 + mt) * 512); // a(s+2)
#pragma unroll
        for (int nt = 0; nt < 4; ++nt)
#pragma unroll
            for (int mt = 0; mt < 4; ++mt)
                acc[nt][mt] = __builtin_amdgcn_mfma_f32_16x16x32_f16(
                    a_c[mt], b_c[nt], acc[nt][mt], 0, 0, 0);
#pragma unroll
        for (int nt = 0; nt < 4; ++nt) b_c[nt] = b_n[nt];
        qv1 = qv2; qv2 = qn;
#pragma unroll
        for (int mt = 0; mt < 4; ++mt) { a_c[mt] = a_n[mt]; a_n[mt] = a_nn[mt]; }
    }

    // ---- epilogue: 4-wave reduce over K sub-chunks ----
    // C/D layout: token r = mt*16 + quad*4 + i, feature c = nt*16 + col
#pragma unroll
    for (int nt = 0; nt < 4; ++nt)
#pragma unroll
        for (int mt = 0; mt < 4; ++mt)
#pragma unroll
            for (int i = 0; i < 4; ++i) {
                int r = mt * 16 + quad * 4 + i;
                int c = nt * 16 + col;
                red[(w * 64 + r) * 68 + c] = acc[nt][mt][i];
            }
    __syncthreads();
    float* yp = y_part + (size_t)p * TOKENS * OUT_F;
#pragma unroll
    for (int j = 0; j < 16; ++j) {
        int idx = j * 256 + tid;
        int rr = idx >> 6, cc = idx & 63;
        float s = (red[(0 * 64 + rr) * 68 + cc] + red[(1 * 64 + rr) * 68 + cc])
                + (red[(2 * 64 + rr) * 68 + cc] + red[(3 * 64 + rr) * 68 + cc]);
        yp[(size_t)rr * OUT_F + n0 + cc] = s;
    }
}

// ---------------------------------------------------------------------------
// Kernel 3: fold 4 K-part partials, FWHT, * 1/sqrt(OUT_F) * SV + bias
// ---------------------------------------------------------------------------
__global__ __launch_bounds__(256) void k_fwht_out(const float* __restrict__ y_part,
                                                  const float* __restrict__ SV,
                                                  const float* __restrict__ bias,
                                                  float* __restrict__ out)
{
    __shared__ float buf[256 * 33];
    const int t    = threadIdx.x;
    const int lane = t & 63;
    const int w    = t >> 6;
    const int row  = blockIdx.x;

    const float* y0 = y_part + (size_t)row * OUT_F;
    const size_t ps = (size_t)TOKENS * OUT_F;

    float v[32];
#pragma unroll
    for (int r = 0; r < 32; ++r) {
        int e = r * 256 + t;
        v[r] = (y0[e] + y0[e + ps]) + (y0[e + 2 * ps] + y0[e + 3 * ps]);
    }
#pragma unroll
    for (int h = 1; h < 32; h <<= 1) {
#pragma unroll
        for (int r = 0; r < 32; ++r) {
            if ((r & h) == 0) {
                float a = v[r], b = v[r + h];
                v[r] = a + b;
                v[r + h] = a - b;
            }
        }
    }
#pragma unroll
    for (int m = 1; m < 64; m <<= 1) {
        bool upper = (lane & m) != 0;
#pragma unroll
        for (int r = 0; r < 32; ++r) {
            float p = __shfl_xor(v[r], m, 64);
            v[r] = upper ? (p - v[r]) : (v[r] + p);
        }
    }
#pragma unroll
    for (int r = 0; r < 32; ++r) buf[t * 33 + r] = v[r];
    __syncthreads();
    {
        float s1 = (w & 1) ? -1.f : 1.f;
        float s2 = (w & 2) ? -1.f : 1.f;
        float s3 = s1 * s2;
#pragma unroll
        for (int r = 0; r < 32; ++r) {
            float a0 = buf[(0 * 64 + lane) * 33 + r];
            float a1 = buf[(1 * 64 + lane) * 33 + r];
            float a2 = buf[(2 * 64 + lane) * 33 + r];
            float a3 = buf[(3 * 64 + lane) * 33 + r];
            v[r] = a0 + s1 * a1 + s2 * a2 + s3 * a3;
        }
    }
    const float scale = 0.011048543456039806f;  // 1/sqrt(8192)
    float* oo = out + (size_t)row * OUT_F;
#pragma unroll
    for (int r = 0; r < 32; ++r) {
        int e = r * 256 + t;
        oo[e] = v[r] * scale * SV[e] + bias[e];
    }
}

extern "C" void kernel_launch(void* const* d_in, const int* in_sizes, int n_in,
                              void* d_out, int out_size, void* d_ws, size_t ws_size,
                              hipStream_t stream) {
    const float* x      = (const float*)d_in[0];
    const float* SU     = (const float*)d_in[1];
    const float* SV     = (const float*)d_in[2];
    const float* grid   = (const float*)d_in[3];
    const float* Wscale = (const float*)d_in[4];
    const float* bias   = (const float*)d_in[5];
    const int*   Qidxs  = (const int*)d_in[6];
    float* out = (float*)d_out;

    // ws layout: xh_frag 1 MB | y_part 8 MB | Qpack 32 MB  (total 41 MB)
    _Float16* xh_frag = (_Float16*)d_ws;
    float*    y_part  = (float*)((char*)d_ws + ((size_t)1 << 20));
    int*      Qpack   = (int*)((char*)d_ws + ((size_t)9 << 20));

    k_qpack<<<512, 256, 0, stream>>>(Qidxs, Qpack);
    k_fwht_in<<<TOKENS, 256, 0, stream>>>(x, SU, Wscale, xh_frag);
    k_qgemm<<<512, 256, 0, stream>>>(xh_frag, Qpack, grid, y_part);
    k_fwht_out<<<TOKENS, 256, 0, stream>>>(y_part, SV, bias, out);
}

// Round 7
// 113.002 us; speedup vs baseline: 1.4643x; 1.0748x over previous
//
#include <hip/hip_runtime.h>
#include <hip/hip_bf16.h>

#define TOKENS 64
#define IN_F 8192
#define OUT_F 8192
#define CB 256

typedef _Float16 half8 __attribute__((ext_vector_type(8)));
typedef float f32x4 __attribute__((ext_vector_type(4)));

// ---------------------------------------------------------------------------
// Kernel 1: xh = FWHT(x * SU) * (1/sqrt(IN_F) * Wscale[0])  -> fp16, stored in
// MFMA-A-FRAGMENT ORDER (k2 A-load = 64 lanes x 16B contiguous):
//   xh_frag[((ks*4 + mt)*64 + quad*16 + l15)*8 + j]
//     = xh_row[mt*16 + l15][ks*32 + quad*8 + j]
// ---------------------------------------------------------------------------
__global__ __launch_bounds__(256) void k_fwht_in(const float* __restrict__ x,
                                                 const float* __restrict__ SU,
                                                 const float* __restrict__ Wscale,
                                                 _Float16* __restrict__ xh_frag)
{
    __shared__ float buf[256 * 33];
    __shared__ _Float16 xrowP[256 * 40];
    const int t    = threadIdx.x;
    const int lane = t & 63;
    const int w    = t >> 6;
    const int row  = blockIdx.x;

    float v[32];
    const float* xr = x + row * IN_F;
#pragma unroll
    for (int r = 0; r < 32; ++r) {
        int e = r * 256 + t;
        v[r] = xr[e] * SU[e];
    }
    // FWHT group A: bits 8..12 (register index)
#pragma unroll
    for (int h = 1; h < 32; h <<= 1) {
#pragma unroll
        for (int r = 0; r < 32; ++r) {
            if ((r & h) == 0) {
                float a = v[r], b = v[r + h];
                v[r] = a + b;
                v[r + h] = a - b;
            }
        }
    }
    // FWHT group B: bits 0..5 (lane bits) via shfl_xor
#pragma unroll
    for (int m = 1; m < 64; m <<= 1) {
        bool upper = (lane & m) != 0;
#pragma unroll
        for (int r = 0; r < 32; ++r) {
            float p = __shfl_xor(v[r], m, 64);
            v[r] = upper ? (p - v[r]) : (v[r] + p);
        }
    }
    // FWHT group C: bits 6..7 (wave bits) via LDS H4
#pragma unroll
    for (int r = 0; r < 32; ++r) buf[t * 33 + r] = v[r];
    __syncthreads();
    {
        float s1 = (w & 1) ? -1.f : 1.f;
        float s2 = (w & 2) ? -1.f : 1.f;
        float s3 = s1 * s2;
#pragma unroll
        for (int r = 0; r < 32; ++r) {
            float a0 = buf[(0 * 64 + lane) * 33 + r];
            float a1 = buf[(1 * 64 + lane) * 33 + r];
            float a2 = buf[(2 * 64 + lane) * 33 + r];
            float a3 = buf[(3 * 64 + lane) * 33 + r];
            v[r] = a0 + s1 * a1 + s2 * a2 + s3 * a3;
        }
    }
    const float scale = 0.011048543456039806f * Wscale[0];  // 1/sqrt(8192)*Wscale
#pragma unroll
    for (int r = 0; r < 32; ++r) {
        int idx = (t & 31) + (r * 8 + (t >> 5)) * 40;   // (c&31) + (c>>5)*40
        xrowP[idx] = (_Float16)(v[r] * scale);
    }
    __syncthreads();
    {
        const int mt  = row >> 4;
        const int l15 = row & 15;
        _Float16* base = xh_frag + ((size_t)(t * 4 + mt) * 64 + l15) * 8;
#pragma unroll
        for (int g = 0; g < 4; ++g) {
            half8 val = *(const half8*)&xrowP[t * 40 + g * 8];
            *(half8*)(base + g * 16 * 8) = val;
        }
    }
}

// ---------------------------------------------------------------------------
// Kernel 2: fused dequant GEMM with IN-KERNEL Qidxs staging (R6: k_qpack fused
// in — saves the separate 12 µs kernel + 32 MB write + 32 MB re-read).
// Grid: 512 blocks = 128 n-groups x 4 K-parts; 4 waves split the K-part.
// Wave tile M=64 x N=64, 16x16x32 f16 MFMA, acc 64 VGPR.
//
// Phase A: stage this block's 64-row x 256-int Qidxs slice into LDS.
//   Wave-coalesced: iter i, thread t -> int4 idx4 = i*256+t, r=idx4>>6,
//   c4=idx4&63; one wave reads 1KB contiguous from one row. Stride 261
//   (261%32=5) -> gather ~2-way max conflicts.
// Phase B: K-loop; index fetch = 4x ds_read_b32 from sq (was global int4);
//   B = LDS codebook 16B gather; A = contiguous 1KB global fragment loads.
//   No barriers in the K-loop.
// Epilogue: red ALIASES sq's LDS (needed only after K-loop) -> total static
//   LDS 73.7 KB, 2 blocks/CU (same as R5).
// ---------------------------------------------------------------------------
#define SQ_STRIDE 261
__global__ __launch_bounds__(256, 2) void k_qgemm(const _Float16* __restrict__ xh_frag,
                                                  const int* __restrict__ Qidxs,
                                                  const float* __restrict__ grid,
                                                  float* __restrict__ y_part)
{
    __shared__ __align__(16) _Float16 glds[CB * 8];       // 4 KB fp16 codebook
    // union region: phase A/B -> int sq[64*261] (66.8 KB);
    //               epilogue  -> float red[4*64*68] (69.6 KB)
    __shared__ __align__(16) char uni[4 * 64 * 68 * 4];   // 69632 B
    int*   sq  = (int*)uni;
    float* red = (float*)uni;

    const int tid = threadIdx.x;
    const int g   = blockIdx.x >> 2; // n-group (128)
    const int p   = blockIdx.x & 3;  // K-part (4)
    const int n0  = g * 64;

    // stage codebook -> LDS fp16
    {
        const float4* gp = (const float4*)grid + tid * 2;
        float4 g0 = gp[0];
        float4 g1 = gp[1];
        _Float16* gl = &glds[tid * 8];
        gl[0] = (_Float16)g0.x; gl[1] = (_Float16)g0.y;
        gl[2] = (_Float16)g0.z; gl[3] = (_Float16)g0.w;
        gl[4] = (_Float16)g1.x; gl[5] = (_Float16)g1.y;
        gl[6] = (_Float16)g1.z; gl[7] = (_Float16)g1.w;
    }
    // Phase A: stage Qidxs slice (rows n0..n0+63, int cols p*256..p*256+255)
#pragma unroll
    for (int i = 0; i < 16; ++i) {
        int idx4 = i * 256 + tid;
        int r  = idx4 >> 6;
        int c4 = idx4 & 63;
        int4 vv = *(const int4*)(Qidxs + (size_t)(n0 + r) * 1024 + p * 256 + c4 * 4);
        int* dst = &sq[r * SQ_STRIDE + c4 * 4];
        dst[0] = vv.x; dst[1] = vv.y; dst[2] = vv.z; dst[3] = vv.w;
    }
    __syncthreads();

    const int lane = tid & 63;
    const int w    = tid >> 6;        // wave id -> K sub-chunk
    const int col  = lane & 15;
    const int quad = lane >> 4;

    // index gather from sq: q(s)[nt] = sq[(nt*16+col)*261 + w*64 + s*4 + quad]
    const int cbase = w * 64 + quad;
#define QGATHER(dst4, s)                                              \
    {                                                                 \
        int cc = cbase + (s) * 4;                                     \
        dst4.x = sq[(0 * 16 + col) * SQ_STRIDE + cc];                 \
        dst4.y = sq[(1 * 16 + col) * SQ_STRIDE + cc];                 \
        dst4.z = sq[(2 * 16 + col) * SQ_STRIDE + cc];                 \
        dst4.w = sq[(3 * 16 + col) * SQ_STRIDE + cc];                 \
    }

    // A fragment base: global kstep Ks = p*64 + w*16 + s; frag (s,mt) at +(s*4+mt)*512
    const _Float16* abase = xh_frag + ((size_t)(p * 64 + w * 16) * 4 * 64 + lane) * 8;

    f32x4 acc[4][4] = {};   // [nt][mt]

    // ---- pipeline prologue: b_c = b(0), qv1 = q(1), qv2 = q(2) ----
    int4 qv1, qv2;
    half8 b_c[4];
    {
        int4 qv0;
        QGATHER(qv0, 0);
        QGATHER(qv1, 1);
        QGATHER(qv2, 2);
        b_c[0] = *(const half8*)&glds[qv0.x * 8];
        b_c[1] = *(const half8*)&glds[qv0.y * 8];
        b_c[2] = *(const half8*)&glds[qv0.z * 8];
        b_c[3] = *(const half8*)&glds[qv0.w * 8];
    }
    half8 a_c[4], a_n[4];
#pragma unroll
    for (int mt = 0; mt < 4; ++mt) {
        a_c[mt] = *(const half8*)(abase + (size_t)(0 * 4 + mt) * 512);
        a_n[mt] = *(const half8*)(abase + (size_t)(1 * 4 + mt) * 512);
    }

#pragma unroll 4
    for (int s = 0; s < 16; ++s) {
        const int s3 = (s + 3 < 16 ? s + 3 : 15);
        const int s2 = (s + 2 < 16 ? s + 2 : 15);
        int4 qn;
        QGATHER(qn, s3);                                 // q(s+3), LDS
        half8 b_n[4], a_nn[4];
        b_n[0] = *(const half8*)&glds[qv1.x * 8];        // b(s+1)
        b_n[1] = *(const half8*)&glds[qv1.y * 8];
        b_n[2] = *(const half8*)&glds[qv1.z * 8];
        b_n[3] = *(const half8*)&glds[qv1.w * 8];
#pragma unroll
        for (int mt = 0; mt < 4; ++mt)
            a_nn[mt] = *(const half8*)(abase + (size_t)(s2 * 4 + mt) * 512); // a(s+2)
#pragma unroll
        for (int nt = 0; nt < 4; ++nt)
#pragma unroll
            for (int mt = 0; mt < 4; ++mt)
                acc[nt][mt] = __builtin_amdgcn_mfma_f32_16x16x32_f16(
                    a_c[mt], b_c[nt], acc[nt][mt], 0, 0, 0);
#pragma unroll
        for (int nt = 0; nt < 4; ++nt) b_c[nt] = b_n[nt];
        qv1 = qv2; qv2 = qn;
#pragma unroll
        for (int mt = 0; mt < 4; ++mt) { a_c[mt] = a_n[mt]; a_n[mt] = a_nn[mt]; }
    }

    // ---- epilogue: red aliases sq; barrier ensures all waves left the K-loop
    __syncthreads();
    // C/D layout: token r = mt*16 + quad*4 + i, feature c = nt*16 + col
#pragma unroll
    for (int nt = 0; nt < 4; ++nt)
#pragma unroll
        for (int mt = 0; mt < 4; ++mt)
#pragma unroll
            for (int i = 0; i < 4; ++i) {
                int r = mt * 16 + quad * 4 + i;
                int c = nt * 16 + col;
                red[(w * 64 + r) * 68 + c] = acc[nt][mt][i];
            }
    __syncthreads();
    float* yp = y_part + (size_t)p * TOKENS * OUT_F;
#pragma unroll
    for (int j = 0; j < 16; ++j) {
        int idx = j * 256 + tid;
        int rr = idx >> 6, cc = idx & 63;
        float s = (red[(0 * 64 + rr) * 68 + cc] + red[(1 * 64 + rr) * 68 + cc])
                + (red[(2 * 64 + rr) * 68 + cc] + red[(3 * 64 + rr) * 68 + cc]);
        yp[(size_t)rr * OUT_F + n0 + cc] = s;
    }
#undef QGATHER
}

// ---------------------------------------------------------------------------
// Kernel 3: fold 4 K-part partials, FWHT, * 1/sqrt(OUT_F) * SV + bias
// ---------------------------------------------------------------------------
__global__ __launch_bounds__(256) void k_fwht_out(const float* __restrict__ y_part,
                                                  const float* __restrict__ SV,
                                                  const float* __restrict__ bias,
                                                  float* __restrict__ out)
{
    __shared__ float buf[256 * 33];
    const int t    = threadIdx.x;
    const int lane = t & 63;
    const int w    = t >> 6;
    const int row  = blockIdx.x;

    const float* y0 = y_part + (size_t)row * OUT_F;
    const size_t ps = (size_t)TOKENS * OUT_F;

    float v[32];
#pragma unroll
    for (int r = 0; r < 32; ++r) {
        int e = r * 256 + t;
        v[r] = (y0[e] + y0[e + ps]) + (y0[e + 2 * ps] + y0[e + 3 * ps]);
    }
#pragma unroll
    for (int h = 1; h < 32; h <<= 1) {
#pragma unroll
        for (int r = 0; r < 32; ++r) {
            if ((r & h) == 0) {
                float a = v[r], b = v[r + h];
                v[r] = a + b;
                v[r + h] = a - b;
            }
        }
    }
#pragma unroll
    for (int m = 1; m < 64; m <<= 1) {
        bool upper = (lane & m) != 0;
#pragma unroll
        for (int r = 0; r < 32; ++r) {
            float p = __shfl_xor(v[r], m, 64);
            v[r] = upper ? (p - v[r]) : (v[r] + p);
        }
    }
#pragma unroll
    for (int r = 0; r < 32; ++r) buf[t * 33 + r] = v[r];
    __syncthreads();
    {
        float s1 = (w & 1) ? -1.f : 1.f;
        float s2 = (w & 2) ? -1.f : 1.f;
        float s3 = s1 * s2;
#pragma unroll
        for (int r = 0; r < 32; ++r) {
            float a0 = buf[(0 * 64 + lane) * 33 + r];
            float a1 = buf[(1 * 64 + lane) * 33 + r];
            float a2 = buf[(2 * 64 + lane) * 33 + r];
            float a3 = buf[(3 * 64 + lane) * 33 + r];
            v[r] = a0 + s1 * a1 + s2 * a2 + s3 * a3;
        }
    }
    const float scale = 0.011048543456039806f;  // 1/sqrt(8192)
    float* oo = out + (size_t)row * OUT_F;
#pragma unroll
    for (int r = 0; r < 32; ++r) {
        int e = r * 256 + t;
        oo[e] = v[r] * scale * SV[e] + bias[e];
    }
}

extern "C" void kernel_launch(void* const* d_in, const int* in_sizes, int n_in,
                              void* d_out, int out_size, void* d_ws, size_t ws_size,
                              hipStream_t stream) {
    const float* x      = (const float*)d_in[0];
    const float* SU     = (const float*)d_in[1];
    const float* SV     = (const float*)d_in[2];
    const float* grid   = (const float*)d_in[3];
    const float* Wscale = (const float*)d_in[4];
    const float* bias   = (const float*)d_in[5];
    const int*   Qidxs  = (const int*)d_in[6];
    float* out = (float*)d_out;

    // ws layout: xh_frag 1 MB | y_part 8 MB
    _Float16* xh_frag = (_Float16*)d_ws;
    float*    y_part  = (float*)((char*)d_ws + ((size_t)1 << 20));

    k_fwht_in<<<TOKENS, 256, 0, stream>>>(x, SU, Wscale, xh_frag);
    k_qgemm<<<512, 256, 0, stream>>>(xh_frag, Qidxs, grid, y_part);
    k_fwht_out<<<TOKENS, 256, 0, stream>>>(y_part, SV, bias, out);
}